// Round 5
// baseline (578.404 us; speedup 1.0000x reference)
//
#include <hip/hip_runtime.h>

typedef __bf16 v8bf __attribute__((ext_vector_type(8)));
typedef float  v4f  __attribute__((ext_vector_type(4)));

#define BB_    4
#define LQ_    1024
#define LEN_IN_ 21760
#define BQ_    4096   // BB_*LQ_
#define MV_    87040  // BB_*LEN_IN_
#define NCHUNK_ 5440  // MV_/16
#define NWAVES_ 2048  // 256 blocks * 8 waves

// ---------------------------------------------------------------------------
// transpose_all: 5 weight transposes (fp32 [K][N] -> bf16 [N][K]) as 32x32
// LDS tiles, plus the swizzled val-weight layout (blocks 672..703).
// vwt_sw layout: elem(n,k) -> (k>>3)*2048 + n*8 + (k&7)   (k-major groups)
// ---------------------------------------------------------------------------
__global__ __launch_bounds__(256) void transpose_all(
    const float* __restrict__ off_w, const float* __restrict__ aw_w,
    const float* __restrict__ out_w, const float* __restrict__ w1,
    const float* __restrict__ w2,    const float* __restrict__ val_w,
    __bf16* __restrict__ offawt, __bf16* __restrict__ pwt,
    __bf16* __restrict__ w1t,    __bf16* __restrict__ w2t,
    __bf16* __restrict__ vwt_sw)
{
    const int b = blockIdx.x;
    if (b >= 672) {                       // val_w swizzle: 32 blocks, one per k-group
        const int g = b - 672;            // k = g*8 + e
        const int n = threadIdx.x;        // 256 threads
        v8bf t;
        #pragma unroll
        for (int e = 0; e < 8; ++e)
            t[e] = (__bf16)val_w[(size_t)(g * 8 + e) * 256 + n];
        *(v8bf*)(vwt_sw + (size_t)g * 2048 + n * 8) = t;
        return;
    }
    const float* in; __bf16* out; int K, N, tileid;
    if (b < 64)       { in = off_w; out = offawt;            K = 256;  N = 256;  tileid = b; }
    else if (b < 96)  { in = aw_w;  out = offawt + 256*256;  K = 256;  N = 128;  tileid = b - 64; }
    else if (b < 160) { in = out_w; out = pwt;               K = 256;  N = 256;  tileid = b - 96; }
    else if (b < 416) { in = w1;    out = w1t;               K = 256;  N = 1024; tileid = b - 160; }
    else              { in = w2;    out = w2t;               K = 1024; N = 256;  tileid = b - 416; }
    const int ntn = N >> 5;
    const int k0 = (tileid / ntn) * 32;
    const int n0 = (tileid % ntn) * 32;
    __shared__ float ts[32][33];
    const int r = threadIdx.x >> 5, c = threadIdx.x & 31;
    #pragma unroll
    for (int i = 0; i < 4; ++i)
        ts[r + i * 8][c] = in[(size_t)(k0 + r + i * 8) * N + n0 + c];
    __syncthreads();
    #pragma unroll
    for (int i = 0; i < 4; ++i)
        out[(size_t)(n0 + r + i * 8) * K + k0 + c] = (__bf16)ts[c][r + i * 8];
}

__global__ void bias_cat(const float* __restrict__ a, const float* __restrict__ b,
                         float* __restrict__ out)
{
    const int i = threadIdx.x;           // 384 threads
    out[i] = (i < 256) ? a[i] : b[i - 256];
}

// ---------------------------------------------------------------------------
// val_stream: C[87040][256]bf16 = A[87040][256]fp32 @ B(256x256) + bias.
// Full B in LDS (128 KiB, swizzled k-major), loaded once. No barriers in
// the main loop: each wave owns 16-row chunks, 16 in-flight float4 A-loads,
// 128 MFMA per chunk. 256 blocks x 512 threads = 1 block/CU, 8 waves.
// ---------------------------------------------------------------------------
__global__ __launch_bounds__(512, 1) void val_stream(
    const float* __restrict__ A, const __bf16* __restrict__ Bsw,
    const float* __restrict__ bias, __bf16* __restrict__ C)
{
    __shared__ __bf16 Bs[65536];          // 128 KiB
    const int tid = threadIdx.x;
    #pragma unroll
    for (int i = 0; i < 16; ++i) {
        const int cc = tid + i * 512;     // 8192 x 16B, coalesced both sides
        *(uint4*)(Bs + cc * 8) = *(const uint4*)(Bsw + cc * 8);
    }
    __syncthreads();

    const int wid  = tid >> 6, lane = tid & 63;
    const int lr   = lane & 15;           // A row / C col within frag
    const int lk   = lane >> 4;           // 0..3 k-group
    const int w    = blockIdx.x * 8 + wid;

    float bv[16];
    #pragma unroll
    for (int j = 0; j < 16; ++j) bv[j] = bias[j * 16 + lr];

    for (int c = w; c < NCHUNK_; c += NWAVES_) {
        const float* ap = A + (size_t)(c * 16 + lr) * 256 + lk * 8;
        float4 a[16];
        #pragma unroll
        for (int s = 0; s < 8; ++s) {
            a[2 * s]     = *(const float4*)(ap + s * 32);
            a[2 * s + 1] = *(const float4*)(ap + s * 32 + 4);
        }
        v4f acc[16];
        #pragma unroll
        for (int j = 0; j < 16; ++j) {
            acc[j][0] = 0.f; acc[j][1] = 0.f; acc[j][2] = 0.f; acc[j][3] = 0.f;
        }
        #pragma unroll
        for (int s = 0; s < 8; ++s) {
            v8bf af;
            af[0] = (__bf16)a[2*s].x;   af[1] = (__bf16)a[2*s].y;
            af[2] = (__bf16)a[2*s].z;   af[3] = (__bf16)a[2*s].w;
            af[4] = (__bf16)a[2*s+1].x; af[5] = (__bf16)a[2*s+1].y;
            af[6] = (__bf16)a[2*s+1].z; af[7] = (__bf16)a[2*s+1].w;
            const __bf16* bp = Bs + (s * 4 + lk) * 2048 + lr * 8;
            #pragma unroll
            for (int j = 0; j < 16; ++j) {
                const v8bf bf_ = *(const v8bf*)(bp + j * 128);
                acc[j] = __builtin_amdgcn_mfma_f32_16x16x32_bf16(af, bf_, acc[j], 0, 0, 0);
            }
        }
        __bf16* cp = C + (size_t)(c * 16 + lk * 4) * 256 + lr;
        #pragma unroll
        for (int j = 0; j < 16; ++j)
            #pragma unroll
            for (int r = 0; r < 4; ++r)
                cp[r * 256 + j * 16] = (__bf16)(acc[j][r] + bv[j]);
    }
}

// ---------------------------------------------------------------------------
// Tiled GEMM 128x128 (for FFN1):  C = A(fp32) @ Bt[N][K]^T + bias
// ---------------------------------------------------------------------------
template<bool RELU, bool OUT_BF16>
__global__ __launch_bounds__(256) void gemm_tn(
    const float* __restrict__ A, const __bf16* __restrict__ Bt,
    const float* __restrict__ bias, void* __restrict__ Cv,
    int K, int lda, int ldc)
{
    __shared__ alignas(16) __bf16 As[128][72];
    __shared__ alignas(16) __bf16 Bs[128][72];
    const int tid  = threadIdx.x;
    const int row0 = blockIdx.y * 128;
    const int col0 = blockIdx.x * 128;
    const int lane = tid & 63;
    const int wid  = tid >> 6;
    const int wm   = (wid >> 1) * 64;
    const int wn   = (wid & 1) * 64;
    const int lr   = lane & 15;
    const int lk   = lane >> 4;

    v4f acc[4][4];
    #pragma unroll
    for (int i = 0; i < 4; ++i)
        #pragma unroll
        for (int j = 0; j < 4; ++j) {
            acc[i][j][0] = 0.f; acc[i][j][1] = 0.f; acc[i][j][2] = 0.f; acc[i][j][3] = 0.f;
        }

    const int nkt = K >> 6;
    for (int kt = 0; kt < nkt; ++kt) {
        const int k0 = kt << 6;
        __syncthreads();
        #pragma unroll
        for (int i = 0; i < 4; ++i) {
            const int c  = tid + i * 256;
            const int r  = c >> 3;
            const int cc = c & 7;
            const float* p = A + (size_t)(row0 + r) * lda + k0 + cc * 8;
            const float4 f0 = *(const float4*)p;
            const float4 f1 = *(const float4*)(p + 4);
            v8bf t;
            t[0] = (__bf16)f0.x; t[1] = (__bf16)f0.y; t[2] = (__bf16)f0.z; t[3] = (__bf16)f0.w;
            t[4] = (__bf16)f1.x; t[5] = (__bf16)f1.y; t[6] = (__bf16)f1.z; t[7] = (__bf16)f1.w;
            *(v8bf*)(&As[r][cc * 8]) = t;
            *(uint4*)(&Bs[r][cc * 8]) = *(const uint4*)(Bt + (size_t)(col0 + r) * K + k0 + cc * 8);
        }
        __syncthreads();
        #pragma unroll
        for (int kk = 0; kk < 2; ++kk) {
            v8bf a[4], b[4];
            #pragma unroll
            for (int i = 0; i < 4; ++i) a[i] = *(const v8bf*)(&As[wm + i * 16 + lr][kk * 32 + lk * 8]);
            #pragma unroll
            for (int j = 0; j < 4; ++j) b[j] = *(const v8bf*)(&Bs[wn + j * 16 + lr][kk * 32 + lk * 8]);
            #pragma unroll
            for (int i = 0; i < 4; ++i)
                #pragma unroll
                for (int j = 0; j < 4; ++j)
                    acc[i][j] = __builtin_amdgcn_mfma_f32_16x16x32_bf16(a[i], b[j], acc[i][j], 0, 0, 0);
        }
    }

    float bv[4];
    #pragma unroll
    for (int j = 0; j < 4; ++j) bv[j] = bias[col0 + wn + j * 16 + lr];
    #pragma unroll
    for (int i = 0; i < 4; ++i)
        #pragma unroll
        for (int j = 0; j < 4; ++j) {
            const int col = col0 + wn + j * 16 + lr;
            #pragma unroll
            for (int r = 0; r < 4; ++r) {
                const int row = row0 + wm + i * 16 + lk * 4 + r;
                float v = acc[i][j][r] + bv[j];
                if constexpr (RELU) v = fmaxf(v, 0.f);
                if constexpr (OUT_BF16) ((__bf16*)Cv)[(size_t)row * ldc + col] = (__bf16)v;
                else                    ((float*)Cv)[(size_t)row * ldc + col] = v;
            }
        }
}

// ---------------------------------------------------------------------------
// Tiled GEMM 64x128 (small GEMMs). AMODE: 0 = fp32, 1 = fp32 a+a2, 2 = bf16.
// ---------------------------------------------------------------------------
template<int AMODE, bool OUT_BF16>
__global__ __launch_bounds__(256) void gemm_tn64(
    const void* __restrict__ Av, const void* __restrict__ A2v,
    const __bf16* __restrict__ Bt, const float* __restrict__ bias,
    void* __restrict__ Cv, int K, int lda, int ldc)
{
    __shared__ alignas(16) __bf16 As[64][72];
    __shared__ alignas(16) __bf16 Bs[128][72];
    const int tid  = threadIdx.x;
    const int row0 = blockIdx.y * 64;
    const int col0 = blockIdx.x * 128;
    const int lane = tid & 63;
    const int wid  = tid >> 6;
    const int wm   = wid * 16;
    const int lr   = lane & 15;
    const int lk   = lane >> 4;

    v4f acc[8];
    #pragma unroll
    for (int j = 0; j < 8; ++j) { acc[j][0]=0.f; acc[j][1]=0.f; acc[j][2]=0.f; acc[j][3]=0.f; }

    const int nkt = K >> 6;
    for (int kt = 0; kt < nkt; ++kt) {
        const int k0 = kt << 6;
        __syncthreads();
        #pragma unroll
        for (int i = 0; i < 2; ++i) {          // A: 64x64 = 512 chunks
            const int c  = tid + i * 256;
            const int r  = c >> 3;
            const int cc = c & 7;
            if constexpr (AMODE == 2) {
                const __bf16* Ab = (const __bf16*)Av;
                *(uint4*)(&As[r][cc * 8]) = *(const uint4*)(Ab + (size_t)(row0 + r) * lda + k0 + cc * 8);
            } else {
                const float* p = (const float*)Av + (size_t)(row0 + r) * lda + k0 + cc * 8;
                float4 f0 = *(const float4*)p;
                float4 f1 = *(const float4*)(p + 4);
                if constexpr (AMODE == 1) {
                    const float* q = (const float*)A2v + (size_t)(row0 + r) * lda + k0 + cc * 8;
                    const float4 g0 = *(const float4*)q;
                    const float4 g1 = *(const float4*)(q + 4);
                    f0.x += g0.x; f0.y += g0.y; f0.z += g0.z; f0.w += g0.w;
                    f1.x += g1.x; f1.y += g1.y; f1.z += g1.z; f1.w += g1.w;
                }
                v8bf t;
                t[0] = (__bf16)f0.x; t[1] = (__bf16)f0.y; t[2] = (__bf16)f0.z; t[3] = (__bf16)f0.w;
                t[4] = (__bf16)f1.x; t[5] = (__bf16)f1.y; t[6] = (__bf16)f1.z; t[7] = (__bf16)f1.w;
                *(v8bf*)(&As[r][cc * 8]) = t;
            }
        }
        #pragma unroll
        for (int i = 0; i < 4; ++i) {          // B: 128x64 = 1024 chunks
            const int c  = tid + i * 256;
            const int r  = c >> 3;
            const int cc = c & 7;
            *(uint4*)(&Bs[r][cc * 8]) = *(const uint4*)(Bt + (size_t)(col0 + r) * K + k0 + cc * 8);
        }
        __syncthreads();
        #pragma unroll
        for (int kk = 0; kk < 2; ++kk) {
            const v8bf a = *(const v8bf*)(&As[wm + lr][kk * 32 + lk * 8]);
            #pragma unroll
            for (int j = 0; j < 8; ++j) {
                const v8bf b = *(const v8bf*)(&Bs[j * 16 + lr][kk * 32 + lk * 8]);
                acc[j] = __builtin_amdgcn_mfma_f32_16x16x32_bf16(a, b, acc[j], 0, 0, 0);
            }
        }
    }

    #pragma unroll
    for (int j = 0; j < 8; ++j) {
        const int col = col0 + j * 16 + lr;
        const float bvj = bias[col];
        #pragma unroll
        for (int r = 0; r < 4; ++r) {
            const int row = row0 + wm + lk * 4 + r;
            const float v = acc[j][r] + bvj;
            if constexpr (OUT_BF16) ((__bf16*)Cv)[(size_t)row * ldc + col] = (__bf16)v;
            else                    ((float*)Cv)[(size_t)row * ldc + col] = v;
        }
    }
}

// ---------------------------------------------------------------------------
__global__ __launch_bounds__(256) void samp_prep(
    const float* __restrict__ offaw,   // [BQ][384]: 256 off | 128 aw
    const float* __restrict__ refp,    // [B][LQ][NL][2]
    float* __restrict__ samp)          // [BQ*8][16][3] = {x, y, w}
{
    const int t  = blockIdx.x * 256 + threadIdx.x;   // 32768
    const int bq = t >> 3;
    const int h  = t & 7;
    const float* base = offaw + (size_t)bq * 384;
    const float* awp  = base + 256 + h * 16;

    float e[16];
    float m = -1e30f;
    #pragma unroll
    for (int j = 0; j < 16; ++j) m = fmaxf(m, awp[j]);
    float s = 0.f;
    #pragma unroll
    for (int j = 0; j < 16; ++j) { e[j] = __expf(awp[j] - m); s += e[j]; }
    const float inv = 1.f / s;

    const float SZ[4] = {128.f, 64.f, 32.f, 16.f};
    float* sp = samp + (size_t)t * 48;
    #pragma unroll
    for (int l = 0; l < 4; ++l) {
        const float rx = refp[(size_t)bq * 8 + l * 2 + 0];
        const float ry = refp[(size_t)bq * 8 + l * 2 + 1];
        const float W = SZ[l];
        #pragma unroll
        for (int p = 0; p < 4; ++p) {
            const float ox = base[h * 32 + l * 8 + p * 2 + 0];
            const float oy = base[h * 32 + l * 8 + p * 2 + 1];
            sp[(l * 4 + p) * 3 + 0] = (rx + ox * (1.f / W)) * W - 0.5f;
            sp[(l * 4 + p) * 3 + 1] = (ry + oy * (1.f / W)) * W - 0.5f;
            sp[(l * 4 + p) * 3 + 2] = e[l * 4 + p] * inv;
        }
    }
}

__global__ __launch_bounds__(256) void ms_sample(
    const __bf16* __restrict__ val,    // [B][LEN_IN][256] bf16
    const float* __restrict__ samp,    // [BQ*8][16][3]
    float* __restrict__ out)           // [BQ][256]
{
    const int g    = blockIdx.x * 8 + (threadIdx.x >> 5);
    const int lane = threadIdx.x & 31;
    const int bq   = g >> 3;
    const int h    = g & 7;
    const int b    = bq >> 10;

    const int Wi[4] = {128, 64, 32, 16};
    const int st[4] = {0, 16384, 20480, 21504};
    const float* sp = samp + (size_t)g * 48;
    const __bf16* vb = val + (size_t)b * LEN_IN_ * 256 + h * 32 + lane;

    float acc = 0.f;
    #pragma unroll
    for (int l = 0; l < 4; ++l) {
        const int W = Wi[l];
        const __bf16* vl = vb + (size_t)st[l] * 256;
        #pragma unroll
        for (int p = 0; p < 4; ++p) {
            const float x  = sp[(l * 4 + p) * 3 + 0];
            const float y  = sp[(l * 4 + p) * 3 + 1];
            const float aw = sp[(l * 4 + p) * 3 + 2];
            const float xf = floorf(x), yf = floorf(y);
            const float fx = x - xf, fy = y - yf;
            const int x0 = (int)xf, y0 = (int)yf;
            const float okx0 = (x0 >= 0 && x0 < W) ? 1.f : 0.f;
            const float okx1 = (x0 + 1 >= 0 && x0 + 1 < W) ? 1.f : 0.f;
            const float oky0 = (y0 >= 0 && y0 < W) ? 1.f : 0.f;
            const float oky1 = (y0 + 1 >= 0 && y0 + 1 < W) ? 1.f : 0.f;
            const int x0c = min(max(x0, 0), W - 1);
            const int x1c = min(max(x0 + 1, 0), W - 1);
            const int y0c = min(max(y0, 0), W - 1);
            const int y1c = min(max(y0 + 1, 0), W - 1);
            const float v00 = (float)vl[(size_t)(y0c * W + x0c) * 256];
            const float v10 = (float)vl[(size_t)(y0c * W + x1c) * 256];
            const float v01 = (float)vl[(size_t)(y1c * W + x0c) * 256];
            const float v11 = (float)vl[(size_t)(y1c * W + x1c) * 256];
            acc += aw * ((1.f - fx) * (1.f - fy) * okx0 * oky0 * v00
                       + fx * (1.f - fy) * okx1 * oky0 * v10
                       + (1.f - fx) * fy * okx0 * oky1 * v01
                       + fx * fy * okx1 * oky1 * v11);
        }
    }
    out[(size_t)bq * 256 + h * 32 + lane] = acc;
}

__global__ __launch_bounds__(256) void ln_residual(
    const float* __restrict__ a, const float* __restrict__ d,
    const float* __restrict__ g, const float* __restrict__ be,
    float* __restrict__ out)
{
    const int row  = blockIdx.x * 4 + (threadIdx.x >> 6);
    const int lane = threadIdx.x & 63;
    const size_t base = (size_t)row * 256 + lane * 4;
    const float4 av = *(const float4*)(a + base);
    const float4 dv = *(const float4*)(d + base);
    float x0 = av.x + dv.x, x1 = av.y + dv.y, x2 = av.z + dv.z, x3 = av.w + dv.w;
    float s  = x0 + x1 + x2 + x3;
    float sq = x0 * x0 + x1 * x1 + x2 * x2 + x3 * x3;
    #pragma unroll
    for (int m = 1; m < 64; m <<= 1) { s += __shfl_xor(s, m); sq += __shfl_xor(sq, m); }
    const float mean = s * (1.f / 256.f);
    const float var  = sq * (1.f / 256.f) - mean * mean;
    const float inv  = rsqrtf(var + 1e-5f);
    const float4 gv = *(const float4*)(g + lane * 4);
    const float4 bv = *(const float4*)(be + lane * 4);
    float4 r;
    r.x = (x0 - mean) * inv * gv.x + bv.x;
    r.y = (x1 - mean) * inv * gv.y + bv.y;
    r.z = (x2 - mean) * inv * gv.z + bv.z;
    r.w = (x3 - mean) * inv * gv.w + bv.w;
    *(float4*)(out + base) = r;
}

// ---------------------------------------------------------------------------
extern "C" void kernel_launch(void* const* d_in, const int* in_sizes, int n_in,
                              void* d_out, int out_size, void* d_ws, size_t ws_size,
                              hipStream_t stream)
{
    const float* tgt    = (const float*)d_in[0];
    const float* qpos   = (const float*)d_in[1];
    const float* refp   = (const float*)d_in[2];
    const float* src    = (const float*)d_in[3];
    const float* off_w  = (const float*)d_in[5];
    const float* off_b  = (const float*)d_in[6];
    const float* aw_w   = (const float*)d_in[7];
    const float* aw_b   = (const float*)d_in[8];
    const float* val_w  = (const float*)d_in[9];
    const float* val_b  = (const float*)d_in[10];
    const float* out_w  = (const float*)d_in[11];
    const float* out_b  = (const float*)d_in[12];
    const float* ln_g   = (const float*)d_in[21];
    const float* ln_b   = (const float*)d_in[22];
    const float* w1     = (const float*)d_in[25];
    const float* b1     = (const float*)d_in[26];
    const float* w2     = (const float*)d_in[27];
    const float* b2     = (const float*)d_in[28];
    const float* ln2_g  = (const float*)d_in[29];
    const float* ln2_b  = (const float*)d_in[30];
    float* out = (float*)d_out;

    char* ws = (char*)d_ws;
    size_t woff = 0;
    auto alloc = [&](size_t bytes) { char* p = ws + woff; woff += (bytes + 255) & ~(size_t)255; return p; };

    __bf16* vwt_sw  = (__bf16*)alloc(256 * 256 * 2);
    __bf16* offawt  = (__bf16*)alloc(384 * 256 * 2);
    __bf16* pwt     = (__bf16*)alloc(256 * 256 * 2);
    __bf16* w1t     = (__bf16*)alloc(1024 * 256 * 2);
    __bf16* w2t     = (__bf16*)alloc(256 * 1024 * 2);
    float*  biascat = (float*)alloc(384 * 4);
    __bf16* valb    = (__bf16*)alloc((size_t)MV_ * 256 * 2);
    float*  offaw   = (float*)alloc((size_t)BQ_ * 384 * 4);
    float*  samp    = (float*)alloc((size_t)BQ_ * 8 * 48 * 4);
    float*  sacc    = (float*)alloc((size_t)BQ_ * 256 * 4);
    float*  tproj   = (float*)alloc((size_t)BQ_ * 256 * 4);
    float*  tgtrgb  = (float*)alloc((size_t)BQ_ * 256 * 4);
    __bf16* hbuf    = (__bf16*)alloc((size_t)BQ_ * 1024 * 2);
    float*  t2      = (float*)alloc((size_t)BQ_ * 256 * 4);
    (void)ws_size; (void)in_sizes; (void)n_in; (void)out_size;

    // prep
    transpose_all<<<704, 256, 0, stream>>>(off_w, aw_w, out_w, w1, w2, val_w,
                                           offawt, pwt, w1t, w2t, vwt_sw);
    bias_cat<<<1, 384, 0, stream>>>(off_b, aw_b, biascat);

    // value projection (streaming, B resident in LDS)
    val_stream<<<256, 512, 0, stream>>>(src, vwt_sw, val_b, valb);

    // offsets + attn logits: [4096,384], A = tgt + qpos fused
    gemm_tn64<1, false><<<dim3(3, 64), 256, 0, stream>>>(
        tgt, qpos, offawt, biascat, offaw, 256, 256, 384);

    samp_prep<<<128, 256, 0, stream>>>(offaw, refp, samp);
    ms_sample<<<4096, 256, 0, stream>>>(valb, samp, sacc);

    // output projection
    gemm_tn64<0, false><<<dim3(2, 64), 256, 0, stream>>>(
        sacc, nullptr, pwt, out_b, tproj, 256, 256, 256);

    ln_residual<<<1024, 256, 0, stream>>>(tgt, tproj, ln_g, ln_b, tgtrgb);

    // FFN
    gemm_tn<true, true><<<dim3(8, 32), 256, 0, stream>>>(
        tgtrgb, w1t, b1, hbuf, 256, 256, 1024);
    gemm_tn64<2, false><<<dim3(2, 64), 256, 0, stream>>>(
        hbuf, nullptr, w2t, b2, t2, 1024, 1024, 256);

    ln_residual<<<1024, 256, 0, stream>>>(tgtrgb, t2, ln2_g, ln2_b, out);
}

// Round 6
// 382.670 us; speedup vs baseline: 1.5115x; 1.5115x over previous
//
#include <hip/hip_runtime.h>

typedef __bf16 v8bf __attribute__((ext_vector_type(8)));
typedef float  v4f  __attribute__((ext_vector_type(4)));

#define BB_     4
#define LQ_     1024
#define LEN_IN_ 21760
#define BQ_     4096   // BB_*LQ_
#define MV_     87040  // BB_*LEN_IN_

// ---------------------------------------------------------------------------
// transpose_all: 6 weight transposes (fp32 [K][N] -> bf16 [N][K]) as 32x32
// LDS tiles + bias concat (block 0). Coalesced both sides.
// ---------------------------------------------------------------------------
__global__ __launch_bounds__(256) void transpose_all(
    const float* __restrict__ off_w, const float* __restrict__ aw_w,
    const float* __restrict__ out_w, const float* __restrict__ w1,
    const float* __restrict__ w2,    const float* __restrict__ val_w,
    const float* __restrict__ off_b, const float* __restrict__ aw_b,
    __bf16* __restrict__ offawt, __bf16* __restrict__ pwt,
    __bf16* __restrict__ w1t,    __bf16* __restrict__ w2t,
    __bf16* __restrict__ vwt,    float* __restrict__ biascat)
{
    const int b = blockIdx.x;
    if (b == 0 && threadIdx.x < 384)
        biascat[threadIdx.x] = (threadIdx.x < 256) ? off_b[threadIdx.x]
                                                   : aw_b[threadIdx.x - 256];
    const float* in; __bf16* out; int K, N, tileid;
    if (b < 64)       { in = off_w; out = offawt;           K = 256;  N = 256;  tileid = b; }
    else if (b < 96)  { in = aw_w;  out = offawt + 65536;   K = 256;  N = 128;  tileid = b - 64; }
    else if (b < 160) { in = out_w; out = pwt;              K = 256;  N = 256;  tileid = b - 96; }
    else if (b < 416) { in = w1;    out = w1t;              K = 256;  N = 1024; tileid = b - 160; }
    else if (b < 672) { in = w2;    out = w2t;              K = 1024; N = 256;  tileid = b - 416; }
    else              { in = val_w; out = vwt;              K = 256;  N = 256;  tileid = b - 672; }
    const int ntn = N >> 5;
    const int k0 = (tileid / ntn) * 32;
    const int n0 = (tileid % ntn) * 32;
    __shared__ float ts[32][33];
    const int r = threadIdx.x >> 5, c = threadIdx.x & 31;
    #pragma unroll
    for (int i = 0; i < 4; ++i)
        ts[r + i * 8][c] = in[(size_t)(k0 + r + i * 8) * N + n0 + c];
    __syncthreads();
    #pragma unroll
    for (int i = 0; i < 4; ++i)
        out[(size_t)(n0 + r + i * 8) * K + k0 + c] = (__bf16)ts[c][r + i * 8];
}

// ---------------------------------------------------------------------------
// val_gemm: C[87040][256]bf16 = A[87040][256]fp32 @ Bt[256N][256K]^T + bias.
// Tile 128 rows x 256 cols (full N: no A re-read), 512 thr / 8 waves (2x4),
// BK=64, LDS-staged with stage-early register prefetch (loads for K-tile t+1
// issued before the MFMA phase of tile t -> in flight through compute).
// LDS 55.3 KB -> 2 blocks/CU. grid = 680.
// ---------------------------------------------------------------------------
template<int TAG>
__global__ __launch_bounds__(512) void val_gemm(
    const float* __restrict__ A, const __bf16* __restrict__ Bt,
    const float* __restrict__ bias, __bf16* __restrict__ C)
{
    __shared__ alignas(16) __bf16 As[128][72];
    __shared__ alignas(16) __bf16 Bs[256][72];
    const int tid  = threadIdx.x;
    const int row0 = blockIdx.x * 128;
    const int lane = tid & 63, wid = tid >> 6;
    const int wm   = (wid >> 2) * 64;     // 2 row-groups
    const int wn   = (wid & 3) * 64;      // 4 col-groups
    const int lr   = lane & 15, lk = lane >> 4;

    float4 pa[4]; uint4 pb[4];
    auto LOAD = [&](int kt) {
        const int k0 = kt << 6;
        #pragma unroll
        for (int i = 0; i < 2; ++i) {
            const int c = tid + i * 512, r = c >> 3, cc = c & 7;
            const float* p = A + (size_t)(row0 + r) * 256 + k0 + cc * 8;
            pa[2 * i]     = *(const float4*)p;
            pa[2 * i + 1] = *(const float4*)(p + 4);
        }
        #pragma unroll
        for (int i = 0; i < 4; ++i) {
            const int c = tid + i * 512, r = c >> 3, cc = c & 7;
            pb[i] = *(const uint4*)(Bt + (size_t)r * 256 + k0 + cc * 8);
        }
    };
    auto STORE = [&]() {
        #pragma unroll
        for (int i = 0; i < 2; ++i) {
            const int c = tid + i * 512, r = c >> 3, cc = c & 7;
            const float4 f0 = pa[2 * i], f1 = pa[2 * i + 1];
            v8bf t;
            t[0] = (__bf16)f0.x; t[1] = (__bf16)f0.y; t[2] = (__bf16)f0.z; t[3] = (__bf16)f0.w;
            t[4] = (__bf16)f1.x; t[5] = (__bf16)f1.y; t[6] = (__bf16)f1.z; t[7] = (__bf16)f1.w;
            *(v8bf*)(&As[r][cc * 8]) = t;
        }
        #pragma unroll
        for (int i = 0; i < 4; ++i) {
            const int c = tid + i * 512, r = c >> 3, cc = c & 7;
            *(uint4*)(&Bs[r][cc * 8]) = pb[i];
        }
    };

    v4f acc[4][4];
    #pragma unroll
    for (int i = 0; i < 4; ++i)
        #pragma unroll
        for (int j = 0; j < 4; ++j) {
            acc[i][j][0] = 0.f; acc[i][j][1] = 0.f; acc[i][j][2] = 0.f; acc[i][j][3] = 0.f;
        }

    LOAD(0); STORE(); __syncthreads();
    #pragma unroll
    for (int kt = 0; kt < 4; ++kt) {
        if (kt < 3) LOAD(kt + 1);          // issue next-tile loads BEFORE compute
        #pragma unroll
        for (int kk = 0; kk < 2; ++kk) {
            v8bf a[4], b[4];
            #pragma unroll
            for (int i = 0; i < 4; ++i) a[i] = *(const v8bf*)(&As[wm + i * 16 + lr][kk * 32 + lk * 8]);
            #pragma unroll
            for (int j = 0; j < 4; ++j) b[j] = *(const v8bf*)(&Bs[wn + j * 16 + lr][kk * 32 + lk * 8]);
            #pragma unroll
            for (int i = 0; i < 4; ++i)
                #pragma unroll
                for (int j = 0; j < 4; ++j)
                    acc[i][j] = __builtin_amdgcn_mfma_f32_16x16x32_bf16(a[i], b[j], acc[i][j], 0, 0, 0);
        }
        __syncthreads();
        if (kt < 3) { STORE(); __syncthreads(); }
    }

    float bv[4];
    #pragma unroll
    for (int j = 0; j < 4; ++j) bv[j] = bias[wn + j * 16 + lr];
    #pragma unroll
    for (int i = 0; i < 4; ++i)
        #pragma unroll
        for (int j = 0; j < 4; ++j) {
            const int col = wn + j * 16 + lr;
            #pragma unroll
            for (int r = 0; r < 4; ++r) {
                const int row = row0 + wm + i * 16 + lk * 4 + r;
                C[(size_t)row * 256 + col] = (__bf16)(acc[i][j][r] + bv[j]);
            }
        }
}

// ---------------------------------------------------------------------------
// gemm64: tile 64x128, 4 waves, BK=64, stage-early prefetch.
// AMODE: 0 = fp32 A, 1 = fp32 A+A2 (fused add), 2 = bf16 A.
// ATOMIC: fp32 atomicAdd epilogue (split-K via blockIdx.z; bias only z==0).
// ---------------------------------------------------------------------------
template<int TAG, int AMODE, bool RELU, bool OUT_BF16, bool ATOMIC>
__global__ __launch_bounds__(256) void gemm64(
    const void* __restrict__ Av, const void* __restrict__ A2v,
    const __bf16* __restrict__ Bt, const float* __restrict__ bias,
    void* __restrict__ Cv, int ktiles, int lda, int ldb, int ldc)
{
    __shared__ alignas(16) __bf16 As[64][72];
    __shared__ alignas(16) __bf16 Bs[128][72];
    const int tid  = threadIdx.x;
    const int row0 = blockIdx.y * 64;
    const int col0 = blockIdx.x * 128;
    const int kb   = blockIdx.z * ktiles;
    const int lane = tid & 63, wid = tid >> 6;
    const int wm   = wid * 16;
    const int lr   = lane & 15, lk = lane >> 4;

    float4 pa[4]; float4 pa2[4]; uint4 pab[2]; uint4 pb[4];
    auto LOAD = [&](int kt) {
        const int k0 = kt << 6;
        #pragma unroll
        for (int i = 0; i < 2; ++i) {
            const int c = tid + i * 256, r = c >> 3, cc = c & 7;
            if constexpr (AMODE == 2) {
                pab[i] = *(const uint4*)((const __bf16*)Av + (size_t)(row0 + r) * lda + k0 + cc * 8);
            } else {
                const float* p = (const float*)Av + (size_t)(row0 + r) * lda + k0 + cc * 8;
                pa[2 * i]     = *(const float4*)p;
                pa[2 * i + 1] = *(const float4*)(p + 4);
                if constexpr (AMODE == 1) {
                    const float* q = (const float*)A2v + (size_t)(row0 + r) * lda + k0 + cc * 8;
                    pa2[2 * i]     = *(const float4*)q;
                    pa2[2 * i + 1] = *(const float4*)(q + 4);
                }
            }
        }
        #pragma unroll
        for (int i = 0; i < 4; ++i) {
            const int c = tid + i * 256, r = c >> 3, cc = c & 7;
            pb[i] = *(const uint4*)(Bt + (size_t)(col0 + r) * ldb + k0 + cc * 8);
        }
    };
    auto STORE = [&]() {
        #pragma unroll
        for (int i = 0; i < 2; ++i) {
            const int c = tid + i * 256, r = c >> 3, cc = c & 7;
            if constexpr (AMODE == 2) {
                *(uint4*)(&As[r][cc * 8]) = pab[i];
            } else {
                float4 f0 = pa[2 * i], f1 = pa[2 * i + 1];
                if constexpr (AMODE == 1) {
                    const float4 g0 = pa2[2 * i], g1 = pa2[2 * i + 1];
                    f0.x += g0.x; f0.y += g0.y; f0.z += g0.z; f0.w += g0.w;
                    f1.x += g1.x; f1.y += g1.y; f1.z += g1.z; f1.w += g1.w;
                }
                v8bf t;
                t[0] = (__bf16)f0.x; t[1] = (__bf16)f0.y; t[2] = (__bf16)f0.z; t[3] = (__bf16)f0.w;
                t[4] = (__bf16)f1.x; t[5] = (__bf16)f1.y; t[6] = (__bf16)f1.z; t[7] = (__bf16)f1.w;
                *(v8bf*)(&As[r][cc * 8]) = t;
            }
        }
        #pragma unroll
        for (int i = 0; i < 4; ++i) {
            const int c = tid + i * 256, r = c >> 3, cc = c & 7;
            *(uint4*)(&Bs[r][cc * 8]) = pb[i];
        }
    };

    v4f acc[8];
    #pragma unroll
    for (int j = 0; j < 8; ++j) { acc[j][0] = 0.f; acc[j][1] = 0.f; acc[j][2] = 0.f; acc[j][3] = 0.f; }

    LOAD(kb); STORE(); __syncthreads();
    for (int kt = 0; kt < ktiles; ++kt) {
        const bool more = (kt + 1 < ktiles);
        if (more) LOAD(kb + kt + 1);
        #pragma unroll
        for (int kk = 0; kk < 2; ++kk) {
            const v8bf a = *(const v8bf*)(&As[wm + lr][kk * 32 + lk * 8]);
            #pragma unroll
            for (int j = 0; j < 8; ++j) {
                const v8bf b = *(const v8bf*)(&Bs[j * 16 + lr][kk * 32 + lk * 8]);
                acc[j] = __builtin_amdgcn_mfma_f32_16x16x32_bf16(a, b, acc[j], 0, 0, 0);
            }
        }
        __syncthreads();
        if (more) { STORE(); __syncthreads(); }
    }

    #pragma unroll
    for (int j = 0; j < 8; ++j) {
        const int col = col0 + j * 16 + lr;
        const float bvj = (!ATOMIC || blockIdx.z == 0) ? bias[col] : 0.f;
        #pragma unroll
        for (int r = 0; r < 4; ++r) {
            const int row = row0 + wm + lk * 4 + r;
            float v = acc[j][r] + bvj;
            if constexpr (RELU) v = fmaxf(v, 0.f);
            if constexpr (ATOMIC)
                atomicAdd(&((float*)Cv)[(size_t)row * ldc + col], v);
            else if constexpr (OUT_BF16)
                ((__bf16*)Cv)[(size_t)row * ldc + col] = (__bf16)v;
            else
                ((float*)Cv)[(size_t)row * ldc + col] = v;
        }
    }
}

// ---------------------------------------------------------------------------
// ms_sample: softmax + location prep fused; one 32-lane group per (b,q,head),
// lane = channel. Gathers are 64 B contiguous per instruction.
// ---------------------------------------------------------------------------
__global__ __launch_bounds__(256) void ms_sample(
    const __bf16* __restrict__ val,    // [B][LEN_IN][256] bf16
    const float* __restrict__ offaw,   // [BQ][384]: 256 off | 128 aw logits
    const float* __restrict__ refp,    // [B][LQ][NL][2]
    float* __restrict__ out)           // [BQ][256]
{
    const int g    = blockIdx.x * 8 + (threadIdx.x >> 5);
    const int lane = threadIdx.x & 31;
    const int bq   = g >> 3;
    const int h    = g & 7;
    const int b    = bq >> 10;

    const float* base = offaw + (size_t)bq * 384;
    const float* awp  = base + 256 + h * 16;
    float e[16];
    float m = -1e30f;
    #pragma unroll
    for (int j = 0; j < 16; ++j) m = fmaxf(m, awp[j]);
    float s = 0.f;
    #pragma unroll
    for (int j = 0; j < 16; ++j) { e[j] = __expf(awp[j] - m); s += e[j]; }
    const float inv = 1.f / s;

    const int Wi[4] = {128, 64, 32, 16};
    const int st[4] = {0, 16384, 20480, 21504};
    const __bf16* vb = val + (size_t)b * LEN_IN_ * 256 + h * 32 + lane;

    float acc = 0.f;
    #pragma unroll
    for (int l = 0; l < 4; ++l) {
        const int W = Wi[l];
        const float Wf = (float)W;
        const float rx = refp[(size_t)bq * 8 + l * 2 + 0];
        const float ry = refp[(size_t)bq * 8 + l * 2 + 1];
        const __bf16* vl = vb + (size_t)st[l] * 256;
        #pragma unroll
        for (int p = 0; p < 4; ++p) {
            const float ox = base[h * 32 + l * 8 + p * 2 + 0];
            const float oy = base[h * 32 + l * 8 + p * 2 + 1];
            const float x  = (rx + ox * (1.f / Wf)) * Wf - 0.5f;
            const float y  = (ry + oy * (1.f / Wf)) * Wf - 0.5f;
            const float aw = e[l * 4 + p] * inv;
            const float xf = floorf(x), yf = floorf(y);
            const float fx = x - xf, fy = y - yf;
            const int x0 = (int)xf, y0 = (int)yf;
            const float okx0 = (x0 >= 0 && x0 < W) ? 1.f : 0.f;
            const float okx1 = (x0 + 1 >= 0 && x0 + 1 < W) ? 1.f : 0.f;
            const float oky0 = (y0 >= 0 && y0 < W) ? 1.f : 0.f;
            const float oky1 = (y0 + 1 >= 0 && y0 + 1 < W) ? 1.f : 0.f;
            const int x0c = min(max(x0, 0), W - 1);
            const int x1c = min(max(x0 + 1, 0), W - 1);
            const int y0c = min(max(y0, 0), W - 1);
            const int y1c = min(max(y0 + 1, 0), W - 1);
            const float v00 = (float)vl[(size_t)(y0c * W + x0c) * 256];
            const float v10 = (float)vl[(size_t)(y0c * W + x1c) * 256];
            const float v01 = (float)vl[(size_t)(y1c * W + x0c) * 256];
            const float v11 = (float)vl[(size_t)(y1c * W + x1c) * 256];
            acc += aw * ((1.f - fx) * (1.f - fy) * okx0 * oky0 * v00
                       + fx * (1.f - fy) * okx1 * oky0 * v10
                       + (1.f - fx) * fy * okx0 * oky1 * v01
                       + fx * fy * okx1 * oky1 * v11);
        }
    }
    out[(size_t)bq * 256 + h * 32 + lane] = acc;
}

// ---------------------------------------------------------------------------
template<int TAG>
__global__ __launch_bounds__(256) void ln_res(
    const float* __restrict__ a, const float* __restrict__ d,
    const float* __restrict__ g, const float* __restrict__ be,
    float* __restrict__ out)
{
    const int row  = blockIdx.x * 4 + (threadIdx.x >> 6);
    const int lane = threadIdx.x & 63;
    const size_t base = (size_t)row * 256 + lane * 4;
    const float4 av = *(const float4*)(a + base);
    const float4 dv = *(const float4*)(d + base);
    float x0 = av.x + dv.x, x1 = av.y + dv.y, x2 = av.z + dv.z, x3 = av.w + dv.w;
    float s  = x0 + x1 + x2 + x3;
    float sq = x0 * x0 + x1 * x1 + x2 * x2 + x3 * x3;
    #pragma unroll
    for (int m = 1; m < 64; m <<= 1) { s += __shfl_xor(s, m); sq += __shfl_xor(sq, m); }
    const float mean = s * (1.f / 256.f);
    const float var  = sq * (1.f / 256.f) - mean * mean;
    const float inv  = rsqrtf(var + 1e-5f);
    const float4 gv = *(const float4*)(g + lane * 4);
    const float4 bv = *(const float4*)(be + lane * 4);
    float4 r;
    r.x = (x0 - mean) * inv * gv.x + bv.x;
    r.y = (x1 - mean) * inv * gv.y + bv.y;
    r.z = (x2 - mean) * inv * gv.z + bv.z;
    r.w = (x3 - mean) * inv * gv.w + bv.w;
    *(float4*)(out + base) = r;
}

__global__ __launch_bounds__(256) void zero_f4(float4* __restrict__ p)
{
    p[(size_t)blockIdx.x * 256 + threadIdx.x] = float4{0.f, 0.f, 0.f, 0.f};
}

// ---------------------------------------------------------------------------
extern "C" void kernel_launch(void* const* d_in, const int* in_sizes, int n_in,
                              void* d_out, int out_size, void* d_ws, size_t ws_size,
                              hipStream_t stream)
{
    const float* tgt    = (const float*)d_in[0];
    const float* qpos   = (const float*)d_in[1];
    const float* refp   = (const float*)d_in[2];
    const float* src    = (const float*)d_in[3];
    const float* off_w  = (const float*)d_in[5];
    const float* off_b  = (const float*)d_in[6];
    const float* aw_w   = (const float*)d_in[7];
    const float* aw_b   = (const float*)d_in[8];
    const float* val_w  = (const float*)d_in[9];
    const float* val_b  = (const float*)d_in[10];
    const float* out_w  = (const float*)d_in[11];
    const float* out_b  = (const float*)d_in[12];
    const float* ln_g   = (const float*)d_in[21];
    const float* ln_b   = (const float*)d_in[22];
    const float* w1     = (const float*)d_in[25];
    const float* b1     = (const float*)d_in[26];
    const float* w2     = (const float*)d_in[27];
    const float* b2     = (const float*)d_in[28];
    const float* ln2_g  = (const float*)d_in[29];
    const float* ln2_b  = (const float*)d_in[30];
    float* out = (float*)d_out;

    char* ws = (char*)d_ws;
    size_t woff = 0;
    auto alloc = [&](size_t bytes) { char* p = ws + woff; woff += (bytes + 255) & ~(size_t)255; return p; };

    __bf16* vwt     = (__bf16*)alloc(256 * 256 * 2);
    __bf16* offawt  = (__bf16*)alloc(384 * 256 * 2);
    __bf16* pwt     = (__bf16*)alloc(256 * 256 * 2);
    __bf16* w1t     = (__bf16*)alloc(1024 * 256 * 2);
    __bf16* w2t     = (__bf16*)alloc(256 * 1024 * 2);
    float*  biascat = (float*)alloc(384 * 4);
    __bf16* valb    = (__bf16*)alloc((size_t)MV_ * 256 * 2);
    float*  offaw   = (float*)alloc((size_t)BQ_ * 384 * 4);
    float*  sacc    = (float*)alloc((size_t)BQ_ * 256 * 4);
    float*  tproj   = (float*)alloc((size_t)BQ_ * 256 * 4);
    float*  tgtrgb  = (float*)alloc((size_t)BQ_ * 256 * 4);
    __bf16* hbuf    = (__bf16*)alloc((size_t)BQ_ * 1024 * 2);
    float*  t2      = (float*)alloc((size_t)BQ_ * 256 * 4);
    (void)ws_size; (void)in_sizes; (void)n_in; (void)out_size;

    // prep: all weight transposes + bias concat
    transpose_all<<<736, 256, 0, stream>>>(off_w, aw_w, out_w, w1, w2, val_w,
                                           off_b, aw_b,
                                           offawt, pwt, w1t, w2t, vwt, biascat);

    // value projection (LDS-staged, full-N tile, stage-early prefetch)
    val_gemm<0><<<680, 512, 0, stream>>>(src, vwt, val_b, valb);

    // offsets + attn logits: [4096,384], A = tgt + qpos fused
    gemm64<1, 1, false, false, false><<<dim3(3, 64), 256, 0, stream>>>(
        tgt, qpos, offawt, biascat, offaw, 4, 256, 256, 384);

    // fused softmax + deformable sampling
    ms_sample<<<4096, 256, 0, stream>>>(valb, offaw, refp, sacc);

    // output projection
    gemm64<2, 0, false, false, false><<<dim3(2, 64), 256, 0, stream>>>(
        sacc, nullptr, pwt, out_b, tproj, 4, 256, 256, 256);

    // LN1
    ln_res<0><<<1024, 256, 0, stream>>>(tgt, tproj, ln_g, ln_b, tgtrgb);

    // FFN1 (ReLU, bf16 out)
    gemm64<3, 0, true, true, false><<<dim3(8, 64), 256, 0, stream>>>(
        tgtrgb, nullptr, w1t, b1, hbuf, 4, 256, 256, 1024);

    // FFN2: split-K=4 with fp32 atomics onto zeroed t2
    zero_f4<<<1024, 256, 0, stream>>>((float4*)t2);
    gemm64<4, 2, false, false, true><<<dim3(2, 64, 4), 256, 0, stream>>>(
        hbuf, nullptr, w2t, b2, t2, 4, 1024, 1024, 256);

    // LN2 -> output
    ln_res<1><<<1024, 256, 0, stream>>>(tgtrgb, t2, ln2_g, ln2_b, out);
}